// Round 3
// baseline (459.503 us; speedup 1.0000x reference)
//
#include <hip/hip_runtime.h>

// MuliHeadedMaskedSelfAttention: B=2, T=2048, C=1024, H=16, DK=64, OUT=1024
// Precision plan: logit path (x->Q/K projection and QK^T) uses split-bf16
// (hi+lo, 3-term MFMA) for fp32-equivalent accuracy; V/P/O paths plain bf16.

typedef unsigned short u16;
typedef __attribute__((ext_vector_type(8))) short bf16x8;
typedef __attribute__((ext_vector_type(4))) float f32x4;

__device__ inline u16 f2bf(float f) {
  union { float f; unsigned u; } v; v.f = f;
  unsigned r = v.u + 0x7FFFu + ((v.u >> 16) & 1u);  // RNE
  return (u16)(r >> 16);
}
__device__ inline float bf2f(u16 h) {
  union { unsigned u; float f; } v; v.u = ((unsigned)h) << 16;
  return v.f;
}

// ---- split-cast fp32 -> (hi, lo) bf16, 4 elems/thread
__global__ __launch_bounds__(256) void split_cast(const float* __restrict__ src,
                                                  u16* __restrict__ hi,
                                                  u16* __restrict__ lo, int n) {
  int i = (blockIdx.x * 256 + threadIdx.x) * 4;
  if (i >= n) return;
  float4 v = *(const float4*)(src + i);
  ushort4 h, l;
  h.x = f2bf(v.x); l.x = f2bf(v.x - bf2f(h.x));
  h.y = f2bf(v.y); l.y = f2bf(v.y - bf2f(h.y));
  h.z = f2bf(v.z); l.z = f2bf(v.z - bf2f(h.z));
  h.w = f2bf(v.w); l.w = f2bf(v.w - bf2f(h.w));
  *(ushort4*)(hi + i) = h;
  *(ushort4*)(lo + i) = l;
}

// ---- transpose 1024x1024 fp32 -> bf16 (Wt[n][c] = W[c][n]), plain
__global__ __launch_bounds__(256) void transpose_cast(const float* __restrict__ W,
                                                      u16* __restrict__ Wt) {
  __shared__ float tile[32][33];
  int bx = blockIdx.x * 32, by = blockIdx.y * 32;
  int tx = threadIdx.x, ty = threadIdx.y;
#pragma unroll
  for (int j = 0; j < 32; j += 8)
    tile[ty + j][tx] = W[(size_t)(by + ty + j) * 1024 + bx + tx];
  __syncthreads();
#pragma unroll
  for (int j = 0; j < 32; j += 8)
    Wt[(size_t)(bx + ty + j) * 1024 + by + tx] = f2bf(tile[tx][ty + j]);
}

// ---- transpose + split-cast: hi/lo bf16
__global__ __launch_bounds__(256) void transpose_cast_split(const float* __restrict__ W,
                                                            u16* __restrict__ Wth,
                                                            u16* __restrict__ Wtl) {
  __shared__ float tile[32][33];
  int bx = blockIdx.x * 32, by = blockIdx.y * 32;
  int tx = threadIdx.x, ty = threadIdx.y;
#pragma unroll
  for (int j = 0; j < 32; j += 8)
    tile[ty + j][tx] = W[(size_t)(by + ty + j) * 1024 + bx + tx];
  __syncthreads();
#pragma unroll
  for (int j = 0; j < 32; j += 8) {
    float v = tile[tx][ty + j];
    u16 h = f2bf(v);
    size_t idx = (size_t)(bx + ty + j) * 1024 + by + tx;
    Wth[idx] = h;
    Wtl[idx] = f2bf(v - bf2f(h));
  }
}

// ---- plain GEMM C[M,N] = A[M,K] * Bt[N,K]^T, bf16, MFMA 16x16x32.
// MODE 0: fp32 row-major out. MODE 2: bf16 out at [(b*16+h)*64+d]*2048+t (V^T).
template <int MODE>
__global__ __launch_bounds__(256) void gemm_bt(const u16* __restrict__ A,
                                               const u16* __restrict__ Bt,
                                               void* __restrict__ Cout,
                                               int M, int N, int K) {
  __shared__ u16 As[64][56];
  __shared__ u16 Bs[64][56];
  const int tid = threadIdx.x;
  const int lane = tid & 63, wv = tid >> 6;
  const int quad = lane >> 4, lc = lane & 15;
  const int m0 = blockIdx.y * 64, n0 = blockIdx.x * 64;
  const int lrow = tid >> 2, lkoff = (tid & 3) * 8;
  const u16* Ap = A + (size_t)(m0 + lrow) * K + lkoff;
  const u16* Bp = Bt + (size_t)(n0 + lrow) * K + lkoff;
  f32x4 acc[4];
#pragma unroll
  for (int i = 0; i < 4; i++) acc[i] = (f32x4){0.f, 0.f, 0.f, 0.f};
  for (int kc = 0; kc < K; kc += 32) {
    bf16x8 av = *(const bf16x8*)(Ap + kc);
    bf16x8 bv = *(const bf16x8*)(Bp + kc);
    __syncthreads();
    *(bf16x8*)&As[lrow][lkoff] = av;
    *(bf16x8*)&Bs[lrow][lkoff] = bv;
    __syncthreads();
    bf16x8 af = *(const bf16x8*)&As[wv * 16 + lc][quad * 8];
#pragma unroll
    for (int nt = 0; nt < 4; nt++) {
      bf16x8 bf = *(const bf16x8*)&Bs[nt * 16 + lc][quad * 8];
      acc[nt] = __builtin_amdgcn_mfma_f32_16x16x32_bf16(af, bf, acc[nt], 0, 0, 0);
    }
  }
  const int rbase = wv * 16 + quad * 4;
  if (MODE == 0) {
    float* C = (float*)Cout;
#pragma unroll
    for (int nt = 0; nt < 4; nt++)
#pragma unroll
      for (int r = 0; r < 4; r++)
        C[(size_t)(m0 + rbase + r) * N + n0 + nt * 16 + lc] = acc[nt][r];
  } else {
    u16* C = (u16*)Cout;
#pragma unroll
    for (int nt = 0; nt < 4; nt++)
#pragma unroll
      for (int r = 0; r < 4; r++) {
        int m = m0 + rbase + r, n = n0 + nt * 16 + lc;
        int b = m >> 11, t = m & 2047, h = n >> 6, d = n & 63;
        size_t idx = ((((size_t)(b * 16 + h) * 64) + d) << 11) + t;
        C[idx] = f2bf(acc[nt][r]);
      }
  }
}

// ---- split GEMM for Q/K projection: C = (Ah+Al)(Bh+Bl)^T (3-term),
// output hi/lo bf16 at [(b*16+h)*2048+t]*64+d. M=4096,N=1024,K=1024.
__global__ __launch_bounds__(256) void gemm_qk_split(const u16* __restrict__ Ah,
                                                     const u16* __restrict__ Al,
                                                     const u16* __restrict__ Bh,
                                                     const u16* __restrict__ Bl,
                                                     u16* __restrict__ Chi,
                                                     u16* __restrict__ Clo) {
  __shared__ u16 Ash[64][56], Asl[64][56], Bsh[64][56], Bsl[64][56];
  const int K = 1024;
  const int tid = threadIdx.x;
  const int lane = tid & 63, wv = tid >> 6;
  const int quad = lane >> 4, lc = lane & 15;
  const int m0 = blockIdx.y * 64, n0 = blockIdx.x * 64;
  const int lrow = tid >> 2, lkoff = (tid & 3) * 8;
  const u16* Ahp = Ah + (size_t)(m0 + lrow) * K + lkoff;
  const u16* Alp = Al + (size_t)(m0 + lrow) * K + lkoff;
  const u16* Bhp = Bh + (size_t)(n0 + lrow) * K + lkoff;
  const u16* Blp = Bl + (size_t)(n0 + lrow) * K + lkoff;
  f32x4 acc[4];
#pragma unroll
  for (int i = 0; i < 4; i++) acc[i] = (f32x4){0.f, 0.f, 0.f, 0.f};
  for (int kc = 0; kc < K; kc += 32) {
    bf16x8 ahv = *(const bf16x8*)(Ahp + kc);
    bf16x8 alv = *(const bf16x8*)(Alp + kc);
    bf16x8 bhv = *(const bf16x8*)(Bhp + kc);
    bf16x8 blv = *(const bf16x8*)(Blp + kc);
    __syncthreads();
    *(bf16x8*)&Ash[lrow][lkoff] = ahv;
    *(bf16x8*)&Asl[lrow][lkoff] = alv;
    *(bf16x8*)&Bsh[lrow][lkoff] = bhv;
    *(bf16x8*)&Bsl[lrow][lkoff] = blv;
    __syncthreads();
    bf16x8 afh = *(const bf16x8*)&Ash[wv * 16 + lc][quad * 8];
    bf16x8 afl = *(const bf16x8*)&Asl[wv * 16 + lc][quad * 8];
#pragma unroll
    for (int nt = 0; nt < 4; nt++) {
      bf16x8 bfh = *(const bf16x8*)&Bsh[nt * 16 + lc][quad * 8];
      bf16x8 bfl = *(const bf16x8*)&Bsl[nt * 16 + lc][quad * 8];
      acc[nt] = __builtin_amdgcn_mfma_f32_16x16x32_bf16(afh, bfh, acc[nt], 0, 0, 0);
      acc[nt] = __builtin_amdgcn_mfma_f32_16x16x32_bf16(afh, bfl, acc[nt], 0, 0, 0);
      acc[nt] = __builtin_amdgcn_mfma_f32_16x16x32_bf16(afl, bfh, acc[nt], 0, 0, 0);
    }
  }
  const int rbase = wv * 16 + quad * 4;
#pragma unroll
  for (int nt = 0; nt < 4; nt++)
#pragma unroll
    for (int r = 0; r < 4; r++) {
      int m = m0 + rbase + r, n = n0 + nt * 16 + lc;
      int b = m >> 11, t = m & 2047, h = n >> 6, d = n & 63;
      size_t idx = ((((size_t)(b * 16 + h) * 2048) + t) << 6) + d;
      float v = acc[nt][r];
      u16 hv = f2bf(v);
      Chi[idx] = hv;
      Clo[idx] = f2bf(v - bf2f(hv));
    }
}

// ---- flash attention with split-bf16 Q,K for the QK^T logits.
// Qh/Ql,Kh/Kl: [BH][2048][64] bf16. Vt: [BH][64][2048] bf16. O16: [B*T][1024] bf16.
__global__ __launch_bounds__(256) void attn(const u16* __restrict__ Qh,
                                            const u16* __restrict__ Ql,
                                            const u16* __restrict__ Kh,
                                            const u16* __restrict__ Kl,
                                            const u16* __restrict__ Vt,
                                            u16* __restrict__ O16) {
  __shared__ u16 Ps[4][16][56];
  const int tid = threadIdx.x;
  const int lane = tid & 63, wv = tid >> 6;
  const int quad = lane >> 4, lc = lane & 15;
  const int gw = blockIdx.x * 4 + wv;
  const int bh = gw & 31, qt = gw >> 5;
  const int t0 = qt * 16;
  const size_t qoff = ((size_t)bh * 2048 + t0) * 64 + lc * 64 + quad * 8;
  bf16x8 qh0 = *(const bf16x8*)(Qh + qoff);
  bf16x8 qh1 = *(const bf16x8*)(Qh + qoff + 32);
  bf16x8 ql0 = *(const bf16x8*)(Ql + qoff);
  bf16x8 ql1 = *(const bf16x8*)(Ql + qoff + 32);
  f32x4 o[4];
#pragma unroll
  for (int i = 0; i < 4; i++) o[i] = (f32x4){0.f, 0.f, 0.f, 0.f};
  float mi[4], li[4];
#pragma unroll
  for (int r = 0; r < 4; r++) { mi[r] = -3.0e38f; li[r] = 0.f; }
  for (int z0 = 0; z0 <= t0; z0 += 32) {
    f32x4 s[2];
#pragma unroll
    for (int nt = 0; nt < 2; nt++) {
      s[nt] = (f32x4){0.f, 0.f, 0.f, 0.f};
      int zr = z0 + nt * 16 + lc;
      if (zr > 2047) zr = 2047;  // clamp; masked anyway
      const size_t koff = ((size_t)bh * 2048 + zr) * 64 + quad * 8;
      bf16x8 kh0 = *(const bf16x8*)(Kh + koff);
      bf16x8 kh1 = *(const bf16x8*)(Kh + koff + 32);
      bf16x8 kl0 = *(const bf16x8*)(Kl + koff);
      bf16x8 kl1 = *(const bf16x8*)(Kl + koff + 32);
      s[nt] = __builtin_amdgcn_mfma_f32_16x16x32_bf16(qh0, kh0, s[nt], 0, 0, 0);
      s[nt] = __builtin_amdgcn_mfma_f32_16x16x32_bf16(qh1, kh1, s[nt], 0, 0, 0);
      s[nt] = __builtin_amdgcn_mfma_f32_16x16x32_bf16(qh0, kl0, s[nt], 0, 0, 0);
      s[nt] = __builtin_amdgcn_mfma_f32_16x16x32_bf16(qh1, kl1, s[nt], 0, 0, 0);
      s[nt] = __builtin_amdgcn_mfma_f32_16x16x32_bf16(ql0, kh0, s[nt], 0, 0, 0);
      s[nt] = __builtin_amdgcn_mfma_f32_16x16x32_bf16(ql1, kh1, s[nt], 0, 0, 0);
    }
#pragma unroll
    for (int r = 0; r < 4; r++) {
      int gt = t0 + quad * 4 + r;
      float a0 = s[0][r] * 8.0f;  // faithful: multiply by sqrt(d_k)
      if (z0 + lc > gt) a0 = -3.0e38f;
      float a1 = s[1][r] * 8.0f;
      if (z0 + 16 + lc > gt) a1 = -3.0e38f;
      float mx = fmaxf(a0, a1);
#pragma unroll
      for (int off = 1; off < 16; off <<= 1) mx = fmaxf(mx, __shfl_xor(mx, off));
      float mnew = fmaxf(mi[r], mx);
      float alpha = __expf(mi[r] - mnew);
      float p0 = __expf(a0 - mnew), p1 = __expf(a1 - mnew);
      float rs = p0 + p1;
#pragma unroll
      for (int off = 1; off < 16; off <<= 1) rs += __shfl_xor(rs, off);
      li[r] = li[r] * alpha + rs;
      mi[r] = mnew;
#pragma unroll
      for (int dt = 0; dt < 4; dt++) o[dt][r] *= alpha;  // only row r's component
      Ps[wv][quad * 4 + r][lc] = f2bf(p0);
      Ps[wv][quad * 4 + r][16 + lc] = f2bf(p1);
    }
    __syncthreads();  // P store -> P frag read (uniform trip count per block)
    bf16x8 pf = *(const bf16x8*)&Ps[wv][lc][quad * 8];
#pragma unroll
    for (int dt = 0; dt < 4; dt++) {
      const u16* Vp = Vt + ((size_t)bh * 64 + dt * 16 + lc) * 2048 + z0 + quad * 8;
      bf16x8 vf = *(const bf16x8*)Vp;  // tail over-read: 32B slack after Vt
      o[dt] = __builtin_amdgcn_mfma_f32_16x16x32_bf16(pf, vf, o[dt], 0, 0, 0);
    }
    __syncthreads();  // protect Ps before next iteration
  }
  const int b = bh >> 4, h = bh & 15;
#pragma unroll
  for (int dt = 0; dt < 4; dt++)
#pragma unroll
    for (int r = 0; r < 4; r++) {
      int t = t0 + quad * 4 + r;
      O16[((size_t)(b * 2048 + t)) * 1024 + h * 64 + dt * 16 + lc] =
          f2bf(o[dt][r] / li[r]);
    }
}

extern "C" void kernel_launch(void* const* d_in, const int* in_sizes, int n_in,
                              void* d_out, int out_size, void* d_ws, size_t ws_size,
                              hipStream_t stream) {
  const float* x  = (const float*)d_in[0];
  const float* wq = (const float*)d_in[1];
  const float* wk = (const float*)d_in[2];
  const float* wv = (const float*)d_in[3];
  const float* wo = (const float*)d_in[4];

  char* w = (char*)d_ws;
  const size_t MB = 1u << 20;
  u16* Xh  = (u16*)(w + 0 * MB);   // 8MB (dead after projections; O16 reuses)
  u16* Xl  = (u16*)(w + 8 * MB);   // 8MB
  u16* Wqh = (u16*)(w + 16 * MB);  // 2MB each
  u16* Wql = (u16*)(w + 18 * MB);
  u16* Wkh = (u16*)(w + 20 * MB);
  u16* Wkl = (u16*)(w + 22 * MB);
  u16* Wvt = (u16*)(w + 24 * MB);
  u16* Wot = (u16*)(w + 26 * MB);
  u16* Qhb = (u16*)(w + 28 * MB);  // [32][2048][64] bf16, 8MB
  u16* Qlb = (u16*)(w + 36 * MB);
  u16* Khb = (u16*)(w + 44 * MB);
  u16* Klb = (u16*)(w + 52 * MB);
  u16* Vtb = (u16*)(w + 60 * MB);  // 8MB + 32B tail slack (within 68MB cap)
  u16* O16 = (u16*)(w + 0 * MB);   // reuse Xh region after projections

  hipLaunchKernelGGL(split_cast, dim3(4096), dim3(256), 0, stream, x, Xh, Xl, 4194304);
  dim3 tb(32, 8), tg(32, 32);
  hipLaunchKernelGGL(transpose_cast_split, tg, tb, 0, stream, wq, Wqh, Wql);
  hipLaunchKernelGGL(transpose_cast_split, tg, tb, 0, stream, wk, Wkh, Wkl);
  hipLaunchKernelGGL(transpose_cast, tg, tb, 0, stream, wv, Wvt);
  hipLaunchKernelGGL(transpose_cast, tg, tb, 0, stream, wo, Wot);

  dim3 gg(16, 64), gb(256);
  hipLaunchKernelGGL(gemm_qk_split, gg, gb, 0, stream, Xh, Xl, Wqh, Wql, Qhb, Qlb);
  hipLaunchKernelGGL(gemm_qk_split, gg, gb, 0, stream, Xh, Xl, Wkh, Wkl, Khb, Klb);
  hipLaunchKernelGGL((gemm_bt<2>), gg, gb, 0, stream, Xh, Wvt, (void*)Vtb, 4096, 1024, 1024);

  hipLaunchKernelGGL(attn, dim3(1024), dim3(256), 0, stream, Qhb, Qlb, Khb, Klb, Vtb, O16);

  hipLaunchKernelGGL((gemm_bt<0>), gg, gb, 0, stream, O16, Wot, d_out, 4096, 1024, 1024);
}

// Round 5
// 355.367 us; speedup vs baseline: 1.2930x; 1.2930x over previous
//
#include <hip/hip_runtime.h>

// MuliHeadedMaskedSelfAttention: B=2, T=2048, C=1024, H=16, DK=64, OUT=1024
// Logit path (Q/K projection, QK^T) in split-bf16 (3-term MFMA) for fp32-class
// accuracy; V/P/O plain bf16. Q (ONLY Q) pre-scaled by 8 = sqrt(d_k) multiply.
// GEMMs: 128-col tiles + global_load_lds(16B), m97 structure. Attention:
// 1-wave blocks, longest-first, barrier-free, K-prefetch software pipeline.

typedef unsigned short u16;
typedef unsigned int u32;
typedef __attribute__((ext_vector_type(8))) short bf16x8;
typedef __attribute__((ext_vector_type(4))) float f32x4;

__device__ inline u16 f2bf(float f) {
  union { float f; unsigned u; } v; v.f = f;
  unsigned r = v.u + 0x7FFFu + ((v.u >> 16) & 1u);  // RNE
  return (u16)(r >> 16);
}
__device__ inline float bf2f(u16 h) {
  union { unsigned u; float f; } v; v.u = ((unsigned)h) << 16;
  return v.f;
}
__device__ inline void glds16(const u16* g, u16* s) {
  __builtin_amdgcn_global_load_lds(
      (const __attribute__((address_space(1))) u32*)g,
      (__attribute__((address_space(3))) u32*)s, 16, 0, 0);
}

// ---- split-cast fp32 -> (hi, lo) bf16, 4 elems/thread
__global__ __launch_bounds__(256) void split_cast(const float* __restrict__ src,
                                                  u16* __restrict__ hi,
                                                  u16* __restrict__ lo, int n) {
  int i = (blockIdx.x * 256 + threadIdx.x) * 4;
  if (i >= n) return;
  float4 v = *(const float4*)(src + i);
  ushort4 h, l;
  h.x = f2bf(v.x); l.x = f2bf(v.x - bf2f(h.x));
  h.y = f2bf(v.y); l.y = f2bf(v.y - bf2f(h.y));
  h.z = f2bf(v.z); l.z = f2bf(v.z - bf2f(h.z));
  h.w = f2bf(v.w); l.w = f2bf(v.w - bf2f(h.w));
  *(ushort4*)(hi + i) = h;
  *(ushort4*)(lo + i) = l;
}

// ---- transpose 1024x1024 fp32 -> bf16 (Wt[n][c] = W[c][n])
__global__ __launch_bounds__(256) void transpose_cast(const float* __restrict__ W,
                                                      u16* __restrict__ Wt) {
  __shared__ float tile[32][33];
  int bx = blockIdx.x * 32, by = blockIdx.y * 32;
  int tx = threadIdx.x, ty = threadIdx.y;
#pragma unroll
  for (int j = 0; j < 32; j += 8)
    tile[ty + j][tx] = W[(size_t)(by + ty + j) * 1024 + bx + tx];
  __syncthreads();
#pragma unroll
  for (int j = 0; j < 32; j += 8)
    Wt[(size_t)(bx + ty + j) * 1024 + by + tx] = f2bf(tile[tx][ty + j]);
}

// ---- transpose + split-cast
__global__ __launch_bounds__(256) void transpose_cast_split(const float* __restrict__ W,
                                                            u16* __restrict__ Wth,
                                                            u16* __restrict__ Wtl) {
  __shared__ float tile[32][33];
  int bx = blockIdx.x * 32, by = blockIdx.y * 32;
  int tx = threadIdx.x, ty = threadIdx.y;
#pragma unroll
  for (int j = 0; j < 32; j += 8)
    tile[ty + j][tx] = W[(size_t)(by + ty + j) * 1024 + bx + tx];
  __syncthreads();
#pragma unroll
  for (int j = 0; j < 32; j += 8) {
    float v = tile[tx][ty + j];
    u16 h = f2bf(v);
    size_t idx = (size_t)(bx + ty + j) * 1024 + by + tx;
    Wth[idx] = h;
    Wtl[idx] = f2bf(v - bf2f(h));
  }
}

// ---- fused QKV projection. 128x128 tile, BK=32, global_load_lds staging.
// z=0: Q (split, scale 8, hi/lo out), z=1: K (split, NO scale), z=2: V (plain, V^T out).
__global__ __launch_bounds__(256) void gemm_qkv(
    const u16* __restrict__ Xh, const u16* __restrict__ Xl,
    const u16* __restrict__ Wqh, const u16* __restrict__ Wql,
    const u16* __restrict__ Wkh, const u16* __restrict__ Wkl,
    const u16* __restrict__ Wvt,
    u16* __restrict__ Qh, u16* __restrict__ Ql,
    u16* __restrict__ Kh, u16* __restrict__ Kl,
    u16* __restrict__ Vt) {
  __shared__ u16 S[4][128][32];  // Ah, Al, Bh, Bl (8KB each), no pad (glds layout)
  const int K = 1024;
  const int z = blockIdx.z;
  const bool split = (z < 2);
  const u16* Bh = (z == 0) ? Wqh : (z == 1) ? Wkh : Wvt;
  const u16* Bl = (z == 0) ? Wql : Wkl;  // dead for z==2
  const int tid = threadIdx.x;
  const int lane = tid & 63, wv = tid >> 6;
  const int quad = lane >> 4, lc = lane & 15;
  const int m0 = blockIdx.y * 128, n0 = blockIdx.x * 128;
  const int wm = (wv >> 1) * 64, wn = (wv & 1) * 64;
  const int lrow = lane >> 2, lk = (lane & 3) * 8;
  // wave wv stages 16-row blocks {wv*32, wv*32+16} of each tile
  const u16* a0p = Xh + (size_t)(m0 + wv * 32 + lrow) * K + lk;
  const u16* a1p = a0p + 16 * K;
  const u16* al0p = Xl + (size_t)(m0 + wv * 32 + lrow) * K + lk;
  const u16* al1p = al0p + 16 * K;
  const u16* b0p = Bh + (size_t)(n0 + wv * 32 + lrow) * K + lk;
  const u16* b1p = b0p + 16 * K;
  const u16* bl0p = split ? (Bl + (size_t)(n0 + wv * 32 + lrow) * K + lk) : b0p;
  const u16* bl1p = bl0p + 16 * K;
  u16* sA0 = &S[0][wv * 32][0];      u16* sA1 = &S[0][wv * 32 + 16][0];
  u16* sAl0 = &S[1][wv * 32][0];     u16* sAl1 = &S[1][wv * 32 + 16][0];
  u16* sB0 = &S[2][wv * 32][0];      u16* sB1 = &S[2][wv * 32 + 16][0];
  u16* sBl0 = &S[3][wv * 32][0];     u16* sBl1 = &S[3][wv * 32 + 16][0];
  f32x4 acc[4][4];
#pragma unroll
  for (int i = 0; i < 4; i++)
#pragma unroll
    for (int j = 0; j < 4; j++) acc[i][j] = (f32x4){0.f, 0.f, 0.f, 0.f};
  for (int kc = 0; kc < K; kc += 32) {
    __syncthreads();  // previous iteration's reads done
    glds16(a0p + kc, sA0); glds16(a1p + kc, sA1);
    glds16(b0p + kc, sB0); glds16(b1p + kc, sB1);
    if (split) {
      glds16(al0p + kc, sAl0); glds16(al1p + kc, sAl1);
      glds16(bl0p + kc, sBl0); glds16(bl1p + kc, sBl1);
    }
    __syncthreads();  // drains vmcnt (glds) per barrier semantics
    bf16x8 ah[4], al[4];
#pragma unroll
    for (int mt = 0; mt < 4; mt++)
      ah[mt] = *(const bf16x8*)&S[0][wm + mt * 16 + lc][quad * 8];
    if (split) {
#pragma unroll
      for (int mt = 0; mt < 4; mt++)
        al[mt] = *(const bf16x8*)&S[1][wm + mt * 16 + lc][quad * 8];
    }
#pragma unroll
    for (int nt = 0; nt < 4; nt++) {
      bf16x8 bfh = *(const bf16x8*)&S[2][wn + nt * 16 + lc][quad * 8];
#pragma unroll
      for (int mt = 0; mt < 4; mt++)
        acc[mt][nt] = __builtin_amdgcn_mfma_f32_16x16x32_bf16(ah[mt], bfh, acc[mt][nt], 0, 0, 0);
      if (split) {
        bf16x8 bfl = *(const bf16x8*)&S[3][wn + nt * 16 + lc][quad * 8];
#pragma unroll
        for (int mt = 0; mt < 4; mt++) {
          acc[mt][nt] = __builtin_amdgcn_mfma_f32_16x16x32_bf16(ah[mt], bfl, acc[mt][nt], 0, 0, 0);
          acc[mt][nt] = __builtin_amdgcn_mfma_f32_16x16x32_bf16(al[mt], bfh, acc[mt][nt], 0, 0, 0);
        }
      }
    }
  }
  const int rb = quad * 4;
  if (z == 2) {
#pragma unroll
    for (int mt = 0; mt < 4; mt++)
#pragma unroll
      for (int nt = 0; nt < 4; nt++)
#pragma unroll
        for (int r = 0; r < 4; r++) {
          int m = m0 + wm + mt * 16 + rb + r, n = n0 + wn + nt * 16 + lc;
          int b = m >> 11, t = m & 2047, h = n >> 6, d = n & 63;
          Vt[((size_t)(b * 16 + h) * 64 + d) * 2048 + t] = f2bf(acc[mt][nt][r]);
        }
  } else {
    u16* Ch = (z == 0) ? Qh : Kh;
    u16* Cl = (z == 0) ? Ql : Kl;
    const float scale = (z == 0) ? 8.0f : 1.0f;  // fold sqrt(d_k) into Q ONLY
#pragma unroll
    for (int mt = 0; mt < 4; mt++)
#pragma unroll
      for (int nt = 0; nt < 4; nt++)
#pragma unroll
        for (int r = 0; r < 4; r++) {
          int m = m0 + wm + mt * 16 + rb + r, n = n0 + wn + nt * 16 + lc;
          int b = m >> 11, t = m & 2047, h = n >> 6, d = n & 63;
          float v = acc[mt][nt][r] * scale;
          u16 hv = f2bf(v);
          size_t idx = ((size_t)(b * 16 + h) * 2048 + t) * 64 + d;
          Ch[idx] = hv;
          Cl[idx] = f2bf(v - bf2f(hv));
        }
  }
}

// ---- output GEMM: C[4096,1024] fp32 = O16[4096,1024] * Wot[1024,1024]^T.
// 64x128 tile (512 blocks -> 2/CU).
__global__ __launch_bounds__(256) void gemm_out(const u16* __restrict__ A,
                                                const u16* __restrict__ Bt,
                                                float* __restrict__ C) {
  __shared__ u16 Sa[64][32], Sb[128][32];
  const int K = 1024, N = 1024;
  const int tid = threadIdx.x;
  const int lane = tid & 63, wv = tid >> 6;
  const int quad = lane >> 4, lc = lane & 15;
  const int m0 = blockIdx.y * 64, n0 = blockIdx.x * 128;
  const int wm = (wv >> 1) * 32, wn = (wv & 1) * 64;
  const int lrow = lane >> 2, lk = (lane & 3) * 8;
  const u16* ap = A + (size_t)(m0 + wv * 16 + lrow) * K + lk;
  const u16* b0p = Bt + (size_t)(n0 + wv * 32 + lrow) * K + lk;
  const u16* b1p = b0p + 16 * K;
  u16* sA = &Sa[wv * 16][0];
  u16* sB0 = &Sb[wv * 32][0];
  u16* sB1 = &Sb[wv * 32 + 16][0];
  f32x4 acc[2][4];
#pragma unroll
  for (int i = 0; i < 2; i++)
#pragma unroll
    for (int j = 0; j < 4; j++) acc[i][j] = (f32x4){0.f, 0.f, 0.f, 0.f};
  for (int kc = 0; kc < K; kc += 32) {
    __syncthreads();
    glds16(ap + kc, sA);
    glds16(b0p + kc, sB0);
    glds16(b1p + kc, sB1);
    __syncthreads();
    bf16x8 ah[2];
#pragma unroll
    for (int mt = 0; mt < 2; mt++)
      ah[mt] = *(const bf16x8*)&Sa[wm + mt * 16 + lc][quad * 8];
#pragma unroll
    for (int nt = 0; nt < 4; nt++) {
      bf16x8 bfh = *(const bf16x8*)&Sb[wn + nt * 16 + lc][quad * 8];
#pragma unroll
      for (int mt = 0; mt < 2; mt++)
        acc[mt][nt] = __builtin_amdgcn_mfma_f32_16x16x32_bf16(ah[mt], bfh, acc[mt][nt], 0, 0, 0);
    }
  }
#pragma unroll
  for (int mt = 0; mt < 2; mt++)
#pragma unroll
    for (int nt = 0; nt < 4; nt++)
#pragma unroll
      for (int r = 0; r < 4; r++)
        C[(size_t)(m0 + wm + mt * 16 + quad * 4 + r) * N + n0 + wn + nt * 16 + lc] =
            acc[mt][nt][r];
}

// ---- flash attention, 1 wave per block, barrier-free, longest-first.
// Q pre-scaled by 8. Mask only in the final (diagonal) z-step.
__global__ __launch_bounds__(64) void attn(const u16* __restrict__ Qh,
                                           const u16* __restrict__ Ql,
                                           const u16* __restrict__ Kh,
                                           const u16* __restrict__ Kl,
                                           const u16* __restrict__ Vt,
                                           u16* __restrict__ O16) {
  __shared__ u16 Ps[16][56];  // 112B row stride: 16B-aligned rows, 2-way banks
  const int lane = threadIdx.x;
  const int quad = lane >> 4, lc = lane & 15;
  const int bh = blockIdx.x & 31;
  const int qt = 127 - (blockIdx.x >> 5);  // longest first
  const int t0 = qt * 16;
  const size_t kbase = (size_t)bh * 2048 * 64;
  const size_t vbase = (size_t)bh * 64 * 2048;
  const size_t qoff = kbase + (size_t)(t0 + lc) * 64 + quad * 8;
  bf16x8 qh0 = *(const bf16x8*)(Qh + qoff);
  bf16x8 qh1 = *(const bf16x8*)(Qh + qoff + 32);
  bf16x8 ql0 = *(const bf16x8*)(Ql + qoff);
  bf16x8 ql1 = *(const bf16x8*)(Ql + qoff + 32);
  f32x4 o[4];
#pragma unroll
  for (int i = 0; i < 4; i++) o[i] = (f32x4){0.f, 0.f, 0.f, 0.f};
  float mi[4], li[4];
#pragma unroll
  for (int r = 0; r < 4; r++) { mi[r] = -3.0e38f; li[r] = 0.f; }
  const int zlast = t0 & ~31;
  bf16x8 kh[2][2], kl[2][2];
#pragma unroll
  for (int nt = 0; nt < 2; nt++) {
    const u16* p = Kh + kbase + (size_t)(nt * 16 + lc) * 64 + quad * 8;
    const u16* pl = Kl + kbase + (size_t)(nt * 16 + lc) * 64 + quad * 8;
    kh[nt][0] = *(const bf16x8*)p;  kh[nt][1] = *(const bf16x8*)(p + 32);
    kl[nt][0] = *(const bf16x8*)pl; kl[nt][1] = *(const bf16x8*)(pl + 32);
  }
  for (int z0 = 0; z0 <= zlast; z0 += 32) {
    const bool fin = (z0 == zlast);
    bf16x8 vf[4];
#pragma unroll
    for (int dt = 0; dt < 4; dt++)
      vf[dt] = *(const bf16x8*)(Vt + vbase + (size_t)(dt * 16 + lc) * 2048 + z0 + quad * 8);
    f32x4 s0 = (f32x4){0.f, 0.f, 0.f, 0.f}, s1 = s0;
    s0 = __builtin_amdgcn_mfma_f32_16x16x32_bf16(qh0, kh[0][0], s0, 0, 0, 0);
    s0 = __builtin_amdgcn_mfma_f32_16x16x32_bf16(qh1, kh[0][1], s0, 0, 0, 0);
    s0 = __builtin_amdgcn_mfma_f32_16x16x32_bf16(qh0, kl[0][0], s0, 0, 0, 0);
    s0 = __builtin_amdgcn_mfma_f32_16x16x32_bf16(qh1, kl[0][1], s0, 0, 0, 0);
    s0 = __builtin_amdgcn_mfma_f32_16x16x32_bf16(ql0, kh[0][0], s0, 0, 0, 0);
    s0 = __builtin_amdgcn_mfma_f32_16x16x32_bf16(ql1, kh[0][1], s0, 0, 0, 0);
    s1 = __builtin_amdgcn_mfma_f32_16x16x32_bf16(qh0, kh[1][0], s1, 0, 0, 0);
    s1 = __builtin_amdgcn_mfma_f32_16x16x32_bf16(qh1, kh[1][1], s1, 0, 0, 0);
    s1 = __builtin_amdgcn_mfma_f32_16x16x32_bf16(qh0, kl[1][0], s1, 0, 0, 0);
    s1 = __builtin_amdgcn_mfma_f32_16x16x32_bf16(qh1, kl[1][1], s1, 0, 0, 0);
    s1 = __builtin_amdgcn_mfma_f32_16x16x32_bf16(ql0, kh[1][0], s1, 0, 0, 0);
    s1 = __builtin_amdgcn_mfma_f32_16x16x32_bf16(ql1, kh[1][1], s1, 0, 0, 0);
    if (!fin) {  // prefetch next K (overlaps softmax); WAR on kh/kl is reg-renamed
      int zn = z0 + 32;
#pragma unroll
      for (int nt = 0; nt < 2; nt++) {
        const u16* p = Kh + kbase + (size_t)(zn + nt * 16 + lc) * 64 + quad * 8;
        const u16* pl = Kl + kbase + (size_t)(zn + nt * 16 + lc) * 64 + quad * 8;
        kh[nt][0] = *(const bf16x8*)p;  kh[nt][1] = *(const bf16x8*)(p + 32);
        kl[nt][0] = *(const bf16x8*)pl; kl[nt][1] = *(const bf16x8*)(pl + 32);
      }
    }
#pragma unroll
    for (int r = 0; r < 4; r++) {
      float a0 = s0[r], a1 = s1[r];
      if (fin) {  // uniform branch
        int gt = t0 + quad * 4 + r;
        a0 = (z0 + lc > gt) ? -3.0e38f : a0;
        a1 = (z0 + 16 + lc > gt) ? -3.0e38f : a1;
      }
      float mx = fmaxf(a0, a1);
#pragma unroll
      for (int off = 1; off < 16; off <<= 1) mx = fmaxf(mx, __shfl_xor(mx, off));
      float mnew = fmaxf(mi[r], mx);
      float alpha = __expf(mi[r] - mnew);
      float p0 = __expf(a0 - mnew), p1 = __expf(a1 - mnew);
      float rs = p0 + p1;
#pragma unroll
      for (int off = 1; off < 16; off <<= 1) rs += __shfl_xor(rs, off);
      li[r] = li[r] * alpha + rs;
      mi[r] = mnew;
      o[0][r] *= alpha; o[1][r] *= alpha; o[2][r] *= alpha; o[3][r] *= alpha;
      Ps[quad * 4 + r][lc] = f2bf(p0);
      Ps[quad * 4 + r][16 + lc] = f2bf(p1);
    }
    // C-layout -> A-layout via per-wave LDS; intra-wave lgkmcnt ordering only
    bf16x8 pf = *(const bf16x8*)&Ps[lc][quad * 8];
#pragma unroll
    for (int dt = 0; dt < 4; dt++)
      o[dt] = __builtin_amdgcn_mfma_f32_16x16x32_bf16(pf, vf[dt], o[dt], 0, 0, 0);
  }
  const int b = bh >> 4, h = bh & 15;
#pragma unroll
  for (int dt = 0; dt < 4; dt++)
#pragma unroll
    for (int r = 0; r < 4; r++) {
      int t = t0 + quad * 4 + r;
      O16[((size_t)(b * 2048 + t)) * 1024 + h * 64 + dt * 16 + lc] =
          f2bf(o[dt][r] / li[r]);
    }
}

extern "C" void kernel_launch(void* const* d_in, const int* in_sizes, int n_in,
                              void* d_out, int out_size, void* d_ws, size_t ws_size,
                              hipStream_t stream) {
  const float* x  = (const float*)d_in[0];
  const float* wq = (const float*)d_in[1];
  const float* wk = (const float*)d_in[2];
  const float* wv = (const float*)d_in[3];
  const float* wo = (const float*)d_in[4];

  char* w = (char*)d_ws;
  const size_t MB = 1u << 20;
  u16* Xh  = (u16*)(w + 0 * MB);   // 8MB; dead after projections -> O16 reuses
  u16* Xl  = (u16*)(w + 8 * MB);
  u16* Wqh = (u16*)(w + 16 * MB);
  u16* Wql = (u16*)(w + 18 * MB);
  u16* Wkh = (u16*)(w + 20 * MB);
  u16* Wkl = (u16*)(w + 22 * MB);
  u16* Wvt = (u16*)(w + 24 * MB);
  u16* Wot = (u16*)(w + 26 * MB);
  u16* Qhb = (u16*)(w + 28 * MB);  // [32][2048][64] bf16
  u16* Qlb = (u16*)(w + 36 * MB);
  u16* Khb = (u16*)(w + 44 * MB);
  u16* Klb = (u16*)(w + 52 * MB);
  u16* Vtb = (u16*)(w + 60 * MB);  // [32][64][2048] bf16
  u16* O16 = (u16*)(w + 0 * MB);   // reuse Xh region

  hipLaunchKernelGGL(split_cast, dim3(4096), dim3(256), 0, stream, x, Xh, Xl, 4194304);
  dim3 tb(32, 8), tg(32, 32);
  hipLaunchKernelGGL(transpose_cast_split, tg, tb, 0, stream, wq, Wqh, Wql);
  hipLaunchKernelGGL(transpose_cast_split, tg, tb, 0, stream, wk, Wkh, Wkl);
  hipLaunchKernelGGL(transpose_cast, tg, tb, 0, stream, wv, Wvt);
  hipLaunchKernelGGL(transpose_cast, tg, tb, 0, stream, wo, Wot);

  hipLaunchKernelGGL(gemm_qkv, dim3(8, 32, 3), dim3(256), 0, stream,
                     Xh, Xl, Wqh, Wql, Wkh, Wkl, Wvt, Qhb, Qlb, Khb, Klb, Vtb);

  hipLaunchKernelGGL(attn, dim3(4096), dim3(64), 0, stream,
                     Qhb, Qlb, Khb, Klb, Vtb, O16);

  hipLaunchKernelGGL(gemm_out, dim3(8, 64), dim3(256), 0, stream, O16, Wot, (float*)d_out);
}